// Round 1
// baseline (786.761 us; speedup 1.0000x reference)
//
#include <hip/hip_runtime.h>
#include <hip/hip_bf16.h>

#define BB 8
#define NN 16384
#define DD 1024
#define AA 128

typedef __attribute__((ext_vector_type(8))) short bf16x8;
typedef __attribute__((ext_vector_type(4))) float f32x4;
typedef __attribute__((ext_vector_type(4))) unsigned short u16x4;

__device__ __forceinline__ unsigned short f2bf(float x) {
  union { __hip_bfloat16 h; unsigned short u; } cv;
  cv.h = __float2bfloat16(x);
  return cv.u;
}

__device__ __forceinline__ float softplusf(float x) {
  return fmaxf(x, 0.f) + log1pf(expf(-fabsf(x)));
}

// ---------------------------------------------------------------------------
// Kernel 0: convert+transpose W1 -> W1T (bf16, [A=128][D=1024]); zero z and
// out[8..9] (accumulated via atomics later; ws/out are poisoned by harness).
// ---------------------------------------------------------------------------
__global__ __launch_bounds__(256) void k_prep(
    const float* __restrict__ W1, unsigned short* __restrict__ W1T,
    float* __restrict__ zv, float* __restrict__ out) {
  const int gid = blockIdx.x * 256 + threadIdx.x;
  if (gid < BB * DD) zv[gid] = 0.f;
  if (gid == 0) { out[8] = 0.f; out[9] = 0.f; }
  if (gid < DD * AA) {
    const int col = gid >> 10;      // 0..127
    const int k   = gid & 1023;     // 0..1023
    W1T[gid] = f2bf(W1[k * AA + col]);
  }
}

// ---------------------------------------------------------------------------
// Kernel 1: f[b][n] = b2 + sum_a w2[a] * tanh( (X W1)[n][a] + b1[a] )
// MFMA bf16, block tile 128 rows x 128 cols, 4 waves (2x2), wave tile 64x64.
// LDS XOR-swizzled (chunk ^= row&7) so frag ds_read_b128 are ~conflict-free.
// ---------------------------------------------------------------------------
__global__ __launch_bounds__(256) void k_scores(
    const float* __restrict__ X, const unsigned short* __restrict__ W1T,
    const float* __restrict__ b1, const float* __restrict__ w2,
    const float* __restrict__ b2p, float* __restrict__ f) {
  __shared__ unsigned short As[128 * 64];   // [row][k] bf16, swizzled
  __shared__ unsigned short Bs[128 * 64];   // [col][k] bf16, swizzled
  __shared__ float fpart[128];
  const int t = threadIdx.x;
  const int lane = t & 63;
  const int wv = t >> 6;
  const int wr = wv >> 1, wc = wv & 1;
  const int l15 = lane & 15, lg = lane >> 4;
  const size_t row0 = (size_t)blockIdx.x * 128;
  const float* Xb = X + row0 * DD;

  f32x4 zero4 = {0.f, 0.f, 0.f, 0.f};
  f32x4 acc[4][4];
#pragma unroll
  for (int mi = 0; mi < 4; ++mi)
#pragma unroll
    for (int ni = 0; ni < 4; ++ni) acc[mi][ni] = zero4;

  for (int st = 0; st < 16; ++st) {
    const int k0 = st * 64;
    // stage A: 128 rows x 64 k f32 -> bf16, swizzled
#pragma unroll
    for (int j = 0; j < 8; ++j) {
      const int i = t + j * 256;
      const int r = i >> 4, c4 = i & 15;
      const int k = c4 * 4;
      float4 v = *(const float4*)(Xb + (size_t)r * DD + k0 + k);
      u16x4 p;
      p.x = f2bf(v.x); p.y = f2bf(v.y); p.z = f2bf(v.z); p.w = f2bf(v.w);
      const int idx = r * 64 + (((k >> 3) ^ (r & 7)) << 3) + (k & 7);
      *(u16x4*)&As[idx] = p;
    }
    // stage B: from pre-transposed bf16 W1T, 128 cols x 64 k, swizzled
#pragma unroll
    for (int j = 0; j < 4; ++j) {
      const int i = t + j * 256;
      const int col = i >> 3, ch = i & 7;
      bf16x8 vv = *(const bf16x8*)(W1T + (size_t)col * DD + k0 + ch * 8);
      *(bf16x8*)&Bs[col * 64 + ((ch ^ (col & 7)) << 3)] = vv;
    }
    __syncthreads();
#pragma unroll
    for (int ks = 0; ks < 2; ++ks) {
      bf16x8 af[4], bg[4];
      const int chunk = ks * 4 + lg;
#pragma unroll
      for (int mi = 0; mi < 4; ++mi) {
        const int r = wr * 64 + mi * 16 + l15;
        af[mi] = *(const bf16x8*)&As[r * 64 + ((chunk ^ (r & 7)) << 3)];
      }
#pragma unroll
      for (int ni = 0; ni < 4; ++ni) {
        const int c = wc * 64 + ni * 16 + l15;
        bg[ni] = *(const bf16x8*)&Bs[c * 64 + ((chunk ^ (c & 7)) << 3)];
      }
#pragma unroll
      for (int mi = 0; mi < 4; ++mi)
#pragma unroll
        for (int ni = 0; ni < 4; ++ni)
          acc[mi][ni] = __builtin_amdgcn_mfma_f32_16x16x32_bf16(
              af[mi], bg[ni], acc[mi][ni], 0, 0, 0);
    }
    __syncthreads();
  }

  // epilogue: f-row = b2 + sum_cols w2*tanh(acc + b1)
  const float b2 = b2p[0];
  float w2c[4], b1c[4];
#pragma unroll
  for (int ni = 0; ni < 4; ++ni) {
    const int c = wc * 64 + ni * 16 + l15;
    w2c[ni] = w2[c];
    b1c[ni] = b1[c];
  }
  float pr[4][4];
#pragma unroll
  for (int mi = 0; mi < 4; ++mi) {
#pragma unroll
    for (int q = 0; q < 4; ++q) {
      float s = 0.f;
#pragma unroll
      for (int ni = 0; ni < 4; ++ni)
        s += w2c[ni] * tanhf(acc[mi][ni][q] + b1c[ni]);
      s += __shfl_xor(s, 1);
      s += __shfl_xor(s, 2);
      s += __shfl_xor(s, 4);
      s += __shfl_xor(s, 8);
      pr[mi][q] = s;
    }
  }
  if (wc == 1 && l15 == 0) {
#pragma unroll
    for (int mi = 0; mi < 4; ++mi)
#pragma unroll
      for (int q = 0; q < 4; ++q)
        fpart[wr * 64 + mi * 16 + lg * 4 + q] = pr[mi][q];
  }
  __syncthreads();
  if (wc == 0 && l15 == 0) {
#pragma unroll
    for (int mi = 0; mi < 4; ++mi)
#pragma unroll
      for (int q = 0; q < 4; ++q) {
        const int rl = wr * 64 + mi * 16 + lg * 4 + q;
        f[row0 + rl] = pr[mi][q] + fpart[rl] + b2;
      }
  }
}

// ---------------------------------------------------------------------------
// Kernel 2: per bag: masked max m, masked sum-exp Z, top-64 ids, bottom-64 ids
// One block per bag; f row staged in LDS; iterative argmax/argmin with
// lowest-index tie-break (matches jax.lax.top_k).
// ---------------------------------------------------------------------------
__global__ __launch_bounds__(256) void k_select(
    const float* __restrict__ f, const float* __restrict__ mask,
    float* __restrict__ ms, float* __restrict__ Zs, int* __restrict__ sel) {
  __shared__ float fv[NN];
  __shared__ float redv[4];
  __shared__ int redi[4];
  const int b = blockIdx.x;
  const int t = threadIdx.x;
  const int lane = t & 63, w = t >> 6;
  const float* fb = f + (size_t)b * NN;
  const float* kb = mask + (size_t)b * NN;

  float mx = -3.0e38f;
  for (int i = t; i < NN; i += 256) {
    const float v = fb[i];
    fv[i] = v;
    const float mv = kb[i] > 0.f ? v : -1.0e30f;
    mx = fmaxf(mx, mv);
  }
#pragma unroll
  for (int s = 1; s < 64; s <<= 1) mx = fmaxf(mx, __shfl_xor(mx, s));
  if (lane == 0) redv[w] = mx;
  __syncthreads();
  const float m = fmaxf(fmaxf(redv[0], redv[1]), fmaxf(redv[2], redv[3]));
  __syncthreads();

  float se = 0.f;
  for (int i = t; i < NN; i += 256)
    se += kb[i] > 0.f ? expf(fv[i] - m) : 0.f;
#pragma unroll
  for (int s = 1; s < 64; s <<= 1) se += __shfl_xor(se, s);
  if (lane == 0) redv[w] = se;
  __syncthreads();
  if (t == 0) {
    ms[b] = m;
    Zs[b] = redv[0] + redv[1] + redv[2] + redv[3];
  }
  __syncthreads();

  // top-64 (destructive)
  for (int it = 0; it < 64; ++it) {
    float best = -3.0e38f; int bix = NN;
    for (int i = t; i < NN; i += 256) {
      const float v = fv[i];
      if (v > best) { best = v; bix = i; }
    }
#pragma unroll
    for (int s = 1; s < 64; s <<= 1) {
      const float ov = __shfl_xor(best, s);
      const int oi = __shfl_xor(bix, s);
      if (ov > best || (ov == best && oi < bix)) { best = ov; bix = oi; }
    }
    if (lane == 0) { redv[w] = best; redi[w] = bix; }
    __syncthreads();
    if (t == 0) {
      float bv = redv[0]; int bx = redi[0];
      for (int q = 1; q < 4; ++q)
        if (redv[q] > bv || (redv[q] == bv && redi[q] < bx)) { bv = redv[q]; bx = redi[q]; }
      sel[b * 128 + it] = bx;
      fv[bx] = -3.0e38f;
    }
    __syncthreads();
  }

  // reload, bottom-64 (destructive)
  for (int i = t; i < NN; i += 256) fv[i] = fb[i];
  __syncthreads();
  for (int it = 0; it < 64; ++it) {
    float best = 3.0e38f; int bix = NN;
    for (int i = t; i < NN; i += 256) {
      const float v = fv[i];
      if (v < best) { best = v; bix = i; }
    }
#pragma unroll
    for (int s = 1; s < 64; s <<= 1) {
      const float ov = __shfl_xor(best, s);
      const int oi = __shfl_xor(bix, s);
      if (ov < best || (ov == best && oi < bix)) { best = ov; bix = oi; }
    }
    if (lane == 0) { redv[w] = best; redi[w] = bix; }
    __syncthreads();
    if (t == 0) {
      float bv = redv[0]; int bx = redi[0];
      for (int q = 1; q < 4; ++q)
        if (redv[q] < bv || (redv[q] == bv && redi[q] < bx)) { bv = redv[q]; bx = redi[q]; }
      sel[b * 128 + 64 + it] = bx;
      fv[bx] = 3.0e38f;
    }
    __syncthreads();
  }
}

// ---------------------------------------------------------------------------
// Kernel 3: z[b][d] += sum_n softmax-weight(n) * X[b][n][d]   (f32 atomics)
// grid: 8 bags x 64 n-chunks; each block streams 256 rows x 1024 d.
// ---------------------------------------------------------------------------
__global__ __launch_bounds__(256) void k_zacc(
    const float* __restrict__ X, const float* __restrict__ f,
    const float* __restrict__ mask, const float* __restrict__ ms,
    const float* __restrict__ Zs, float* __restrict__ zv) {
  const int b = blockIdx.x >> 6;
  const int chunk = blockIdx.x & 63;
  const int t = threadIdx.x;
  const int d = t * 4;
  const float m = ms[b];
  const float inv = 1.0f / Zs[b];
  const int n0 = chunk * (NN / 64);
  const float* Xb = X + ((size_t)b * NN + n0) * DD;
  const float* fb = f + (size_t)b * NN + n0;
  const float* kb = mask + (size_t)b * NN + n0;
  float4 acc = make_float4(0.f, 0.f, 0.f, 0.f);
#pragma unroll 4
  for (int n = 0; n < NN / 64; ++n) {
    const float wgt = kb[n] > 0.f ? expf(fb[n] - m) * inv : 0.f;
    const float4 x = *(const float4*)(Xb + (size_t)n * DD + d);
    acc.x = fmaf(wgt, x.x, acc.x);
    acc.y = fmaf(wgt, x.y, acc.y);
    acc.z = fmaf(wgt, x.z, acc.z);
    acc.w = fmaf(wgt, x.w, acc.w);
  }
  float* zb = zv + b * DD + d;
  atomicAdd(zb + 0, acc.x);
  atomicAdd(zb + 1, acc.y);
  atomicAdd(zb + 2, acc.z);
  atomicAdd(zb + 3, acc.w);
}

// ---------------------------------------------------------------------------
// Kernel 4: bag_pred, crit_loss, instance smooth-top1-SVM losses.
// One block per bag; one wave per selected row.
// ---------------------------------------------------------------------------
__global__ __launch_bounds__(256) void k_final(
    const float* __restrict__ X, const float* __restrict__ zv,
    const float* __restrict__ Wc, const float* __restrict__ bc,
    const int* __restrict__ labels, const int* __restrict__ sel,
    const float* __restrict__ Wi, const float* __restrict__ bi,
    float* __restrict__ out) {
  const int b = blockIdx.x;
  const int t = threadIdx.x;
  const int lane = t & 63, w = t >> 6;
  __shared__ float sin_[4], sout_[4];
  const int label = labels[b];

  if (w == 0) {
    float s = 0.f;
    const float* zb = zv + b * DD;
#pragma unroll
    for (int j = 0; j < 16; j += 4) {
      const float4 a = *(const float4*)(zb + lane * 16 + j);
      const float4 c = *(const float4*)(Wc + lane * 16 + j);
      s += a.x * c.x + a.y * c.y + a.z * c.z + a.w * c.w;
    }
#pragma unroll
    for (int sh = 1; sh < 64; sh <<= 1) s += __shfl_xor(s, sh);
    if (lane == 0) {
      const float bp = s + bc[0];
      out[b] = bp;
      const float lf = (float)label;
      atomicAdd(out + 8, (softplusf(bp) - bp * lf) * 0.125f);
    }
  }

  const float* Win = Wi + label * (DD * 2);
  const float* Wot = Wi + (1 - label) * (DD * 2);
  const float bin0 = bi[label * 2], bin1 = bi[label * 2 + 1];
  const float bo0 = bi[(1 - label) * 2], bo1 = bi[(1 - label) * 2 + 1];
  float ain = 0.f, aout = 0.f;
  for (int r = w; r < 128; r += 4) {
    const int id = sel[b * 128 + r];
    const float* xr = X + ((size_t)b * NN + id) * DD;
    float p0 = 0.f, p1 = 0.f, p2 = 0.f, p3 = 0.f;
#pragma unroll
    for (int j = 0; j < 16; j += 4) {
      const int d = lane * 16 + j;
      const float4 x = *(const float4*)(xr + d);
      const float4 wa = *(const float4*)(Win + d * 2);
      const float4 wb = *(const float4*)(Win + d * 2 + 4);
      p0 += x.x * wa.x + x.y * wa.z + x.z * wb.x + x.w * wb.z;
      p1 += x.x * wa.y + x.y * wa.w + x.z * wb.y + x.w * wb.w;
      if (r < 64) {
        const float4 oa = *(const float4*)(Wot + d * 2);
        const float4 ob = *(const float4*)(Wot + d * 2 + 4);
        p2 += x.x * oa.x + x.y * oa.z + x.z * ob.x + x.w * ob.z;
        p3 += x.x * oa.y + x.y * oa.w + x.z * ob.y + x.w * ob.w;
      }
    }
#pragma unroll
    for (int sh = 1; sh < 64; sh <<= 1) {
      p0 += __shfl_xor(p0, sh);
      p1 += __shfl_xor(p1, sh);
      p2 += __shfl_xor(p2, sh);
      p3 += __shfl_xor(p3, sh);
    }
    if (lane == 0) {
      const float l0 = p0 + bin0, l1 = p1 + bin1;
      ain += (r < 64) ? softplusf(l0 + 1.f - l1) : softplusf(l1 + 1.f - l0);
      if (r < 64) aout += softplusf((p3 + bo1) + 1.f - (p2 + bo0));
    }
  }
  if (lane == 0) { sin_[w] = ain; sout_[w] = aout; }
  __syncthreads();
  if (t == 0) {
    const float ti = sin_[0] + sin_[1] + sin_[2] + sin_[3];
    const float to = sout_[0] + sout_[1] + sout_[2] + sout_[3];
    atomicAdd(out + 9, ti * (1.0f / 128.0f) + to * (1.0f / 64.0f));
  }
}

// ---------------------------------------------------------------------------

extern "C" void kernel_launch(void* const* d_in, const int* in_sizes, int n_in,
                              void* d_out, int out_size, void* d_ws, size_t ws_size,
                              hipStream_t stream) {
  const float* X      = (const float*)d_in[0];
  const float* mask   = (const float*)d_in[1];
  const int*   labels = (const int*)d_in[2];
  const float* W1     = (const float*)d_in[3];
  const float* b1     = (const float*)d_in[4];
  const float* w2     = (const float*)d_in[5];
  const float* b2     = (const float*)d_in[6];
  const float* Wc     = (const float*)d_in[7];
  const float* bc     = (const float*)d_in[8];
  const float* Wi     = (const float*)d_in[9];
  const float* bi     = (const float*)d_in[10];
  float* out = (float*)d_out;

  float* ws  = (float*)d_ws;
  float* f   = ws;                            // 131072 f32
  float* ms  = ws + 131072;                   // 8
  float* Zs  = ws + 131080;                   // 8
  float* zv  = ws + 131088;                   // 8192
  int*   sel = (int*)(ws + 139280);           // 1024 int
  unsigned short* W1T = (unsigned short*)(ws + 140304);  // 131072 bf16

  k_prep  <<<512,  256, 0, stream>>>(W1, W1T, zv, out);
  k_scores<<<1024, 256, 0, stream>>>(X, W1T, b1, w2, b2, f);
  k_select<<<8,    256, 0, stream>>>(f, mask, ms, Zs, sel);
  k_zacc  <<<512,  256, 0, stream>>>(X, f, mask, ms, Zs, zv);
  k_final <<<8,    256, 0, stream>>>(X, zv, Wc, bc, labels, sel, Wi, bi, out);
}

// Round 2
// 441.968 us; speedup vs baseline: 1.7801x; 1.7801x over previous
//
#include <hip/hip_runtime.h>
#include <hip/hip_bf16.h>

#define BB 8
#define NN 16384
#define DD 1024
#define AA 128

typedef __attribute__((ext_vector_type(8))) short bf16x8;
typedef __attribute__((ext_vector_type(4))) float f32x4;
typedef __attribute__((ext_vector_type(4))) unsigned short u16x4;

__device__ __forceinline__ unsigned short f2bf(float x) {
  union { __hip_bfloat16 h; unsigned short u; } cv;
  cv.h = __float2bfloat16(x);
  return cv.u;
}

__device__ __forceinline__ float softplusf(float x) {
  return fmaxf(x, 0.f) + log1pf(expf(-fabsf(x)));
}

// order-preserving float->uint map (monotone: a<b  <=>  ordu(a)<ordu(b))
__device__ __forceinline__ unsigned int ordu(float x) {
  unsigned int u = __float_as_uint(x);
  return (u & 0x80000000u) ? ~u : (u | 0x80000000u);
}

// LDS index swizzle to break stride-64-float (32-way) bank conflicts
__device__ __forceinline__ int fvx(int i) {
  return i ^ ((i >> 6) & 63);
}

// ---------------------------------------------------------------------------
// Kernel 0: convert+transpose W1 -> W1T (bf16, [A=128][D=1024]); zero z and
// out[8..9].
// ---------------------------------------------------------------------------
__global__ __launch_bounds__(256) void k_prep(
    const float* __restrict__ W1, unsigned short* __restrict__ W1T,
    float* __restrict__ zv, float* __restrict__ out) {
  const int gid = blockIdx.x * 256 + threadIdx.x;
  if (gid < BB * DD) zv[gid] = 0.f;
  if (gid == 0) { out[8] = 0.f; out[9] = 0.f; }
  if (gid < DD * AA) {
    const int col = gid >> 10;      // 0..127
    const int k   = gid & 1023;     // 0..1023
    W1T[gid] = f2bf(W1[k * AA + col]);
  }
}

// ---------------------------------------------------------------------------
// Kernel 1: f[b][n] = b2 + sum_a w2[a] * tanh( (X W1)[n][a] + b1[a] )
// MFMA bf16, block tile 128 rows x 128 cols, 4 waves (2x2), wave tile 64x64.
// ---------------------------------------------------------------------------
__global__ __launch_bounds__(256) void k_scores(
    const float* __restrict__ X, const unsigned short* __restrict__ W1T,
    const float* __restrict__ b1, const float* __restrict__ w2,
    const float* __restrict__ b2p, float* __restrict__ f) {
  __shared__ unsigned short As[128 * 64];   // [row][k] bf16, swizzled
  __shared__ unsigned short Bs[128 * 64];   // [col][k] bf16, swizzled
  __shared__ float fpart[128];
  const int t = threadIdx.x;
  const int lane = t & 63;
  const int wv = t >> 6;
  const int wr = wv >> 1, wc = wv & 1;
  const int l15 = lane & 15, lg = lane >> 4;
  const size_t row0 = (size_t)blockIdx.x * 128;
  const float* Xb = X + row0 * DD;

  f32x4 zero4 = {0.f, 0.f, 0.f, 0.f};
  f32x4 acc[4][4];
#pragma unroll
  for (int mi = 0; mi < 4; ++mi)
#pragma unroll
    for (int ni = 0; ni < 4; ++ni) acc[mi][ni] = zero4;

  for (int st = 0; st < 16; ++st) {
    const int k0 = st * 64;
#pragma unroll
    for (int j = 0; j < 8; ++j) {
      const int i = t + j * 256;
      const int r = i >> 4, c4 = i & 15;
      const int k = c4 * 4;
      float4 v = *(const float4*)(Xb + (size_t)r * DD + k0 + k);
      u16x4 p;
      p.x = f2bf(v.x); p.y = f2bf(v.y); p.z = f2bf(v.z); p.w = f2bf(v.w);
      const int idx = r * 64 + (((k >> 3) ^ (r & 7)) << 3) + (k & 7);
      *(u16x4*)&As[idx] = p;
    }
#pragma unroll
    for (int j = 0; j < 4; ++j) {
      const int i = t + j * 256;
      const int col = i >> 3, ch = i & 7;
      bf16x8 vv = *(const bf16x8*)(W1T + (size_t)col * DD + k0 + ch * 8);
      *(bf16x8*)&Bs[col * 64 + ((ch ^ (col & 7)) << 3)] = vv;
    }
    __syncthreads();
#pragma unroll
    for (int ks = 0; ks < 2; ++ks) {
      bf16x8 af[4], bg[4];
      const int chunk = ks * 4 + lg;
#pragma unroll
      for (int mi = 0; mi < 4; ++mi) {
        const int r = wr * 64 + mi * 16 + l15;
        af[mi] = *(const bf16x8*)&As[r * 64 + ((chunk ^ (r & 7)) << 3)];
      }
#pragma unroll
      for (int ni = 0; ni < 4; ++ni) {
        const int c = wc * 64 + ni * 16 + l15;
        bg[ni] = *(const bf16x8*)&Bs[c * 64 + ((chunk ^ (c & 7)) << 3)];
      }
#pragma unroll
      for (int mi = 0; mi < 4; ++mi)
#pragma unroll
        for (int ni = 0; ni < 4; ++ni)
          acc[mi][ni] = __builtin_amdgcn_mfma_f32_16x16x32_bf16(
              af[mi], bg[ni], acc[mi][ni], 0, 0, 0);
    }
    __syncthreads();
  }

  const float b2 = b2p[0];
  float w2c[4], b1c[4];
#pragma unroll
  for (int ni = 0; ni < 4; ++ni) {
    const int c = wc * 64 + ni * 16 + l15;
    w2c[ni] = w2[c];
    b1c[ni] = b1[c];
  }
  float pr[4][4];
#pragma unroll
  for (int mi = 0; mi < 4; ++mi) {
#pragma unroll
    for (int q = 0; q < 4; ++q) {
      float s = 0.f;
#pragma unroll
      for (int ni = 0; ni < 4; ++ni)
        s += w2c[ni] * tanhf(acc[mi][ni][q] + b1c[ni]);
      s += __shfl_xor(s, 1);
      s += __shfl_xor(s, 2);
      s += __shfl_xor(s, 4);
      s += __shfl_xor(s, 8);
      pr[mi][q] = s;
    }
  }
  if (wc == 1 && l15 == 0) {
#pragma unroll
    for (int mi = 0; mi < 4; ++mi)
#pragma unroll
      for (int q = 0; q < 4; ++q)
        fpart[wr * 64 + mi * 16 + lg * 4 + q] = pr[mi][q];
  }
  __syncthreads();
  if (wc == 0 && l15 == 0) {
#pragma unroll
    for (int mi = 0; mi < 4; ++mi)
#pragma unroll
      for (int q = 0; q < 4; ++q) {
        const int rl = wr * 64 + mi * 16 + lg * 4 + q;
        f[row0 + rl] = pr[mi][q] + fpart[rl] + b2;
      }
  }
}

// ---------------------------------------------------------------------------
// Kernel 2: per bag: masked max m, masked sum-exp Z, top-64 ids, bottom-64 ids.
// One block per bag. Top/bottom-64 via 4-pass byte radix select on
// order-preserving uint keys; ties resolved lowest-index (matches lax.top_k);
// set membership only (loss is permutation-invariant within each group).
// ---------------------------------------------------------------------------
__global__ __launch_bounds__(256) void k_select(
    const float* __restrict__ f, const float* __restrict__ mask,
    float* __restrict__ ms, float* __restrict__ Zs, int* __restrict__ sel) {
  __shared__ float fv[NN];            // swizzled via fvx()
  __shared__ unsigned int hist[256];
  __shared__ unsigned int cnts[256];
  __shared__ float redv[4];
  __shared__ unsigned int sb[4];      // [0]=pref [1]=above [2]=krem [3]=gcnt
  const int b = blockIdx.x;
  const int t = threadIdx.x;
  const int lane = t & 63, w = t >> 6;
  const float* fb = f + (size_t)b * NN;
  const float* kb = mask + (size_t)b * NN;

  // load f into LDS (swizzled) + masked max
  float mx = -3.0e38f;
  for (int i = t; i < NN; i += 256) {
    const float v = fb[i];
    fv[fvx(i)] = v;
    mx = fmaxf(mx, kb[i] > 0.f ? v : -1.0e30f);
  }
#pragma unroll
  for (int s = 1; s < 64; s <<= 1) mx = fmaxf(mx, __shfl_xor(mx, s));
  if (lane == 0) redv[w] = mx;
  __syncthreads();
  const float m = fmaxf(fmaxf(redv[0], redv[1]), fmaxf(redv[2], redv[3]));
  __syncthreads();

  // masked sum-exp
  float se = 0.f;
  for (int i = t; i < NN; i += 256)
    se += kb[i] > 0.f ? expf(fv[fvx(i)] - m) : 0.f;
#pragma unroll
  for (int s = 1; s < 64; s <<= 1) se += __shfl_xor(se, s);
  if (lane == 0) redv[w] = se;
  __syncthreads();
  if (t == 0) {
    ms[b] = m;
    Zs[b] = redv[0] + redv[1] + redv[2] + redv[3];
  }

  // mode 0: top-64 (descending on ordu); mode 1: bottom-64 (descending on ~ordu)
  const int i0 = t * 64;  // contiguous chunk => tie ranks are index-ordered
  for (int mode = 0; mode < 2; ++mode) {
    unsigned int pref = 0u, above = 0u, krem = 64u;
    for (int p = 3; p >= 0; --p) {
      hist[t] = 0u;
      __syncthreads();
      const unsigned int pmask = (p == 3) ? 0u : (0xFFFFFFFFu << ((p + 1) * 8));
      for (int j = 0; j < 64; ++j) {
        unsigned int u = ordu(fv[fvx(i0 + j)]);
        if (mode) u = ~u;
        if ((u & pmask) == pref)
          atomicAdd(&hist[(u >> (p * 8)) & 255u], 1u);
      }
      __syncthreads();
      if (t == 0) {
        unsigned int cum = 0; int bsel = 0;
        for (int bb = 255; bb >= 0; --bb) {
          const unsigned int h = hist[bb];
          if (cum + h >= krem) { bsel = bb; break; }
          cum += h;
        }
        sb[0] = pref | ((unsigned int)bsel << (p * 8));
        sb[1] = above + cum;
        sb[2] = krem - cum;
      }
      __syncthreads();
      pref = sb[0]; above = sb[1]; krem = sb[2];
    }
    // T = pref; 'above' elements strictly greater; take 'krem' ties low-index.
    if (t == 0) sb[3] = 0u;
    __syncthreads();
    const int off = b * 128 + mode * 64;
    unsigned int myties = 0;
    for (int j = 0; j < 64; ++j) {
      unsigned int u = ordu(fv[fvx(i0 + j)]);
      if (mode) u = ~u;
      if (u > pref) {
        const unsigned int pos = atomicAdd(&sb[3], 1u);
        sel[off + pos] = i0 + j;
      } else if (u == pref) {
        myties++;
      }
    }
    cnts[t] = myties;
    __syncthreads();
    if (t == 0) {
      unsigned int run = 0;
      for (int q = 0; q < 256; ++q) {
        const unsigned int c = cnts[q];
        cnts[q] = run;
        run += c;
      }
    }
    __syncthreads();
    unsigned int g = cnts[t];
    for (int j = 0; j < 64; ++j) {
      unsigned int u = ordu(fv[fvx(i0 + j)]);
      if (mode) u = ~u;
      if (u == pref) {
        if (g < krem) sel[off + above + g] = i0 + j;
        g++;
      }
    }
    __syncthreads();
  }
}

// ---------------------------------------------------------------------------
// Kernel 3: z[b][d] += sum_n softmax-weight(n) * X[b][n][d]   (f32 atomics)
// ---------------------------------------------------------------------------
__global__ __launch_bounds__(256) void k_zacc(
    const float* __restrict__ X, const float* __restrict__ f,
    const float* __restrict__ mask, const float* __restrict__ ms,
    const float* __restrict__ Zs, float* __restrict__ zv) {
  const int b = blockIdx.x >> 6;
  const int chunk = blockIdx.x & 63;
  const int t = threadIdx.x;
  const int d = t * 4;
  const float m = ms[b];
  const float inv = 1.0f / Zs[b];
  const int n0 = chunk * (NN / 64);
  const float* Xb = X + ((size_t)b * NN + n0) * DD;
  const float* fb = f + (size_t)b * NN + n0;
  const float* kb = mask + (size_t)b * NN + n0;
  float4 acc = make_float4(0.f, 0.f, 0.f, 0.f);
#pragma unroll 4
  for (int n = 0; n < NN / 64; ++n) {
    const float wgt = kb[n] > 0.f ? expf(fb[n] - m) * inv : 0.f;
    const float4 x = *(const float4*)(Xb + (size_t)n * DD + d);
    acc.x = fmaf(wgt, x.x, acc.x);
    acc.y = fmaf(wgt, x.y, acc.y);
    acc.z = fmaf(wgt, x.z, acc.z);
    acc.w = fmaf(wgt, x.w, acc.w);
  }
  float* zb = zv + b * DD + d;
  atomicAdd(zb + 0, acc.x);
  atomicAdd(zb + 1, acc.y);
  atomicAdd(zb + 2, acc.z);
  atomicAdd(zb + 3, acc.w);
}

// ---------------------------------------------------------------------------
// Kernel 4: bag_pred, crit_loss, instance smooth-top1-SVM losses.
// ---------------------------------------------------------------------------
__global__ __launch_bounds__(256) void k_final(
    const float* __restrict__ X, const float* __restrict__ zv,
    const float* __restrict__ Wc, const float* __restrict__ bc,
    const int* __restrict__ labels, const int* __restrict__ sel,
    const float* __restrict__ Wi, const float* __restrict__ bi,
    float* __restrict__ out) {
  const int b = blockIdx.x;
  const int t = threadIdx.x;
  const int lane = t & 63, w = t >> 6;
  __shared__ float sin_[4], sout_[4];
  const int label = labels[b];

  if (w == 0) {
    float s = 0.f;
    const float* zb = zv + b * DD;
#pragma unroll
    for (int j = 0; j < 16; j += 4) {
      const float4 a = *(const float4*)(zb + lane * 16 + j);
      const float4 c = *(const float4*)(Wc + lane * 16 + j);
      s += a.x * c.x + a.y * c.y + a.z * c.z + a.w * c.w;
    }
#pragma unroll
    for (int sh = 1; sh < 64; sh <<= 1) s += __shfl_xor(s, sh);
    if (lane == 0) {
      const float bp = s + bc[0];
      out[b] = bp;
      const float lf = (float)label;
      atomicAdd(out + 8, (softplusf(bp) - bp * lf) * 0.125f);
    }
  }

  const float* Win = Wi + label * (DD * 2);
  const float* Wot = Wi + (1 - label) * (DD * 2);
  const float bin0 = bi[label * 2], bin1 = bi[label * 2 + 1];
  const float bo0 = bi[(1 - label) * 2], bo1 = bi[(1 - label) * 2 + 1];
  float ain = 0.f, aout = 0.f;
  for (int r = w; r < 128; r += 4) {
    const int id = sel[b * 128 + r];
    const float* xr = X + ((size_t)b * NN + id) * DD;
    float p0 = 0.f, p1 = 0.f, p2 = 0.f, p3 = 0.f;
#pragma unroll
    for (int j = 0; j < 16; j += 4) {
      const int d = lane * 16 + j;
      const float4 x = *(const float4*)(xr + d);
      const float4 wa = *(const float4*)(Win + d * 2);
      const float4 wb = *(const float4*)(Win + d * 2 + 4);
      p0 += x.x * wa.x + x.y * wa.z + x.z * wb.x + x.w * wb.z;
      p1 += x.x * wa.y + x.y * wa.w + x.z * wb.y + x.w * wb.w;
      if (r < 64) {
        const float4 oa = *(const float4*)(Wot + d * 2);
        const float4 ob = *(const float4*)(Wot + d * 2 + 4);
        p2 += x.x * oa.x + x.y * oa.z + x.z * ob.x + x.w * ob.z;
        p3 += x.x * oa.y + x.y * oa.w + x.z * ob.y + x.w * ob.w;
      }
    }
#pragma unroll
    for (int sh = 1; sh < 64; sh <<= 1) {
      p0 += __shfl_xor(p0, sh);
      p1 += __shfl_xor(p1, sh);
      p2 += __shfl_xor(p2, sh);
      p3 += __shfl_xor(p3, sh);
    }
    if (lane == 0) {
      const float l0 = p0 + bin0, l1 = p1 + bin1;
      ain += (r < 64) ? softplusf(l0 + 1.f - l1) : softplusf(l1 + 1.f - l0);
      if (r < 64) aout += softplusf((p3 + bo1) + 1.f - (p2 + bo0));
    }
  }
  if (lane == 0) { sin_[w] = ain; sout_[w] = aout; }
  __syncthreads();
  if (t == 0) {
    const float ti = sin_[0] + sin_[1] + sin_[2] + sin_[3];
    const float to = sout_[0] + sout_[1] + sout_[2] + sout_[3];
    atomicAdd(out + 9, ti * (1.0f / 128.0f) + to * (1.0f / 64.0f));
  }
}

// ---------------------------------------------------------------------------

extern "C" void kernel_launch(void* const* d_in, const int* in_sizes, int n_in,
                              void* d_out, int out_size, void* d_ws, size_t ws_size,
                              hipStream_t stream) {
  const float* X      = (const float*)d_in[0];
  const float* mask   = (const float*)d_in[1];
  const int*   labels = (const int*)d_in[2];
  const float* W1     = (const float*)d_in[3];
  const float* b1     = (const float*)d_in[4];
  const float* w2     = (const float*)d_in[5];
  const float* b2     = (const float*)d_in[6];
  const float* Wc     = (const float*)d_in[7];
  const float* bc     = (const float*)d_in[8];
  const float* Wi     = (const float*)d_in[9];
  const float* bi     = (const float*)d_in[10];
  float* out = (float*)d_out;

  float* ws  = (float*)d_ws;
  float* f   = ws;                            // 131072 f32
  float* ms  = ws + 131072;                   // 8
  float* Zs  = ws + 131080;                   // 8
  float* zv  = ws + 131088;                   // 8192
  int*   sel = (int*)(ws + 139280);           // 1024 int
  unsigned short* W1T = (unsigned short*)(ws + 140304);  // 131072 bf16

  k_prep  <<<512,  256, 0, stream>>>(W1, W1T, zv, out);
  k_scores<<<1024, 256, 0, stream>>>(X, W1T, b1, w2, b2, f);
  k_select<<<8,    256, 0, stream>>>(f, mask, ms, Zs, sel);
  k_zacc  <<<512,  256, 0, stream>>>(X, f, mask, ms, Zs, zv);
  k_final <<<8,    256, 0, stream>>>(X, zv, Wc, bc, labels, sel, Wi, bi, out);
}

// Round 3
// 387.805 us; speedup vs baseline: 2.0288x; 1.1397x over previous
//
#include <hip/hip_runtime.h>
#include <hip/hip_bf16.h>

#define BB 8
#define NN 16384
#define DD 1024
#define AA 128

typedef __attribute__((ext_vector_type(8))) short bf16x8;
typedef __attribute__((ext_vector_type(4))) float f32x4;
typedef __attribute__((ext_vector_type(4))) unsigned short u16x4;

__device__ __forceinline__ unsigned short f2bf(float x) {
  union { __hip_bfloat16 h; unsigned short u; } cv;
  cv.h = __float2bfloat16(x);
  return cv.u;
}

__device__ __forceinline__ float softplusf(float x) {
  return fmaxf(x, 0.f) + log1pf(expf(-fabsf(x)));
}

// order-preserving float->uint map (monotone: a<b  <=>  ordu(a)<ordu(b))
__device__ __forceinline__ unsigned int ordu(float x) {
  unsigned int u = __float_as_uint(x);
  return (u & 0x80000000u) ? ~u : (u | 0x80000000u);
}

// LDS index swizzle to break stride-64-float (32-way) bank conflicts
__device__ __forceinline__ int fvx(int i) {
  return i ^ ((i >> 6) & 63);
}

// ---------------------------------------------------------------------------
// Kernel 0: convert+transpose W1 -> W1T (bf16, [A=128][D=1024]); zero z and
// out[8..9].
// ---------------------------------------------------------------------------
__global__ __launch_bounds__(256) void k_prep(
    const float* __restrict__ W1, unsigned short* __restrict__ W1T,
    float* __restrict__ zv, float* __restrict__ out) {
  const int gid = blockIdx.x * 256 + threadIdx.x;
  if (gid < BB * DD) zv[gid] = 0.f;
  if (gid == 0) { out[8] = 0.f; out[9] = 0.f; }
  if (gid < DD * AA) {
    const int col = gid >> 10;      // 0..127
    const int k   = gid & 1023;     // 0..1023
    W1T[gid] = f2bf(W1[k * AA + col]);
  }
}

// ---------------------------------------------------------------------------
// Kernel 1: f[b][n] = b2 + sum_a w2[a] * tanh( (X W1)[n][a] + b1[a] )
// MFMA bf16, block tile 128 rows x 128 cols, 4 waves (2x2), wave tile 64x64.
// ---------------------------------------------------------------------------
__global__ __launch_bounds__(256) void k_scores(
    const float* __restrict__ X, const unsigned short* __restrict__ W1T,
    const float* __restrict__ b1, const float* __restrict__ w2,
    const float* __restrict__ b2p, float* __restrict__ f) {
  __shared__ unsigned short As[128 * 64];   // [row][k] bf16, swizzled
  __shared__ unsigned short Bs[128 * 64];   // [col][k] bf16, swizzled
  __shared__ float fpart[128];
  const int t = threadIdx.x;
  const int lane = t & 63;
  const int wv = t >> 6;
  const int wr = wv >> 1, wc = wv & 1;
  const int l15 = lane & 15, lg = lane >> 4;
  const size_t row0 = (size_t)blockIdx.x * 128;
  const float* Xb = X + row0 * DD;

  f32x4 zero4 = {0.f, 0.f, 0.f, 0.f};
  f32x4 acc[4][4];
#pragma unroll
  for (int mi = 0; mi < 4; ++mi)
#pragma unroll
    for (int ni = 0; ni < 4; ++ni) acc[mi][ni] = zero4;

  for (int st = 0; st < 16; ++st) {
    const int k0 = st * 64;
#pragma unroll
    for (int j = 0; j < 8; ++j) {
      const int i = t + j * 256;
      const int r = i >> 4, c4 = i & 15;
      const int k = c4 * 4;
      float4 v = *(const float4*)(Xb + (size_t)r * DD + k0 + k);
      u16x4 p;
      p.x = f2bf(v.x); p.y = f2bf(v.y); p.z = f2bf(v.z); p.w = f2bf(v.w);
      const int idx = r * 64 + (((k >> 3) ^ (r & 7)) << 3) + (k & 7);
      *(u16x4*)&As[idx] = p;
    }
#pragma unroll
    for (int j = 0; j < 4; ++j) {
      const int i = t + j * 256;
      const int col = i >> 3, ch = i & 7;
      bf16x8 vv = *(const bf16x8*)(W1T + (size_t)col * DD + k0 + ch * 8);
      *(bf16x8*)&Bs[col * 64 + ((ch ^ (col & 7)) << 3)] = vv;
    }
    __syncthreads();
#pragma unroll
    for (int ks = 0; ks < 2; ++ks) {
      bf16x8 af[4], bg[4];
      const int chunk = ks * 4 + lg;
#pragma unroll
      for (int mi = 0; mi < 4; ++mi) {
        const int r = wr * 64 + mi * 16 + l15;
        af[mi] = *(const bf16x8*)&As[r * 64 + ((chunk ^ (r & 7)) << 3)];
      }
#pragma unroll
      for (int ni = 0; ni < 4; ++ni) {
        const int c = wc * 64 + ni * 16 + l15;
        bg[ni] = *(const bf16x8*)&Bs[c * 64 + ((chunk ^ (c & 7)) << 3)];
      }
#pragma unroll
      for (int mi = 0; mi < 4; ++mi)
#pragma unroll
        for (int ni = 0; ni < 4; ++ni)
          acc[mi][ni] = __builtin_amdgcn_mfma_f32_16x16x32_bf16(
              af[mi], bg[ni], acc[mi][ni], 0, 0, 0);
    }
    __syncthreads();
  }

  const float b2 = b2p[0];
  float w2c[4], b1c[4];
#pragma unroll
  for (int ni = 0; ni < 4; ++ni) {
    const int c = wc * 64 + ni * 16 + l15;
    w2c[ni] = w2[c];
    b1c[ni] = b1[c];
  }
  float pr[4][4];
#pragma unroll
  for (int mi = 0; mi < 4; ++mi) {
#pragma unroll
    for (int q = 0; q < 4; ++q) {
      float s = 0.f;
#pragma unroll
      for (int ni = 0; ni < 4; ++ni)
        s += w2c[ni] * tanhf(acc[mi][ni][q] + b1c[ni]);
      s += __shfl_xor(s, 1);
      s += __shfl_xor(s, 2);
      s += __shfl_xor(s, 4);
      s += __shfl_xor(s, 8);
      pr[mi][q] = s;
    }
  }
  if (wc == 1 && l15 == 0) {
#pragma unroll
    for (int mi = 0; mi < 4; ++mi)
#pragma unroll
      for (int q = 0; q < 4; ++q)
        fpart[wr * 64 + mi * 16 + lg * 4 + q] = pr[mi][q];
  }
  __syncthreads();
  if (wc == 0 && l15 == 0) {
#pragma unroll
    for (int mi = 0; mi < 4; ++mi)
#pragma unroll
      for (int q = 0; q < 4; ++q) {
        const int rl = wr * 64 + mi * 16 + lg * 4 + q;
        f[row0 + rl] = pr[mi][q] + fpart[rl] + b2;
      }
  }
}

// ---------------------------------------------------------------------------
// Kernel 2: per bag: masked max m, masked sum-exp Z, top-64 ids, bottom-64 ids.
// One block per bag. 4-pass byte radix select on order-preserving uint keys
// held in LDS (converted in place). All scans are wave-parallel (__shfl),
// no serial t==0 loops. Ties -> lowest index (matches lax.top_k).
// ---------------------------------------------------------------------------
__global__ __launch_bounds__(256) void k_select(
    const float* __restrict__ f, const float* __restrict__ mask,
    float* __restrict__ ms, float* __restrict__ Zs, int* __restrict__ sel) {
  __shared__ float fv[NN];            // swizzled via fvx(); aliased as uint
  __shared__ unsigned int hist[256];
  __shared__ float redv[4];
  __shared__ unsigned int wq[4];
  __shared__ unsigned int sb[4];      // [0]=pref [1]=above [2]=krem [3]=gcnt
  unsigned int* uv = (unsigned int*)fv;
  const int b = blockIdx.x;
  const int t = threadIdx.x;
  const int lane = t & 63, w = t >> 6;
  const float* fb = f + (size_t)b * NN;
  const float* kb = mask + (size_t)b * NN;

  // load f into LDS (swizzled) + masked max
  float mx = -3.0e38f;
  for (int i = t; i < NN; i += 256) {
    const float v = fb[i];
    fv[fvx(i)] = v;
    mx = fmaxf(mx, kb[i] > 0.f ? v : -1.0e30f);
  }
#pragma unroll
  for (int s = 1; s < 64; s <<= 1) mx = fmaxf(mx, __shfl_xor(mx, s));
  if (lane == 0) redv[w] = mx;
  __syncthreads();
  const float m = fmaxf(fmaxf(redv[0], redv[1]), fmaxf(redv[2], redv[3]));
  __syncthreads();

  // masked sum-exp
  float se = 0.f;
  for (int i = t; i < NN; i += 256)
    se += kb[i] > 0.f ? expf(fv[fvx(i)] - m) : 0.f;
#pragma unroll
  for (int s = 1; s < 64; s <<= 1) se += __shfl_xor(se, s);
  if (lane == 0) redv[w] = se;
  __syncthreads();
  if (t == 0) {
    ms[b] = m;
    Zs[b] = redv[0] + redv[1] + redv[2] + redv[3];
  }
  __syncthreads();

  // convert LDS values to order-preserving uints, in place
  for (int i = t; i < NN; i += 256) {
    const int x = fvx(i);
    uv[x] = ordu(fv[x]);
  }
  // (the hist-zero barrier below also fences this conversion)

  // mode 0: top-64 (descending on u); mode 1: bottom-64 (descending on ~u)
  const int i0 = t * 64;  // contiguous chunk => tie ranks are index-ordered
  for (int mode = 0; mode < 2; ++mode) {
    unsigned int pref = 0u, above = 0u, krem = 64u;
    for (int p = 3; p >= 0; --p) {
      hist[t] = 0u;
      __syncthreads();
      const unsigned int pmask = (p == 3) ? 0u : (0xFFFFFFFFu << ((p + 1) * 8));
      for (int j = 0; j < 64; ++j) {
        unsigned int u = uv[fvx(i0 + j)];
        if (mode) u = ~u;
        if ((u & pmask) == pref)
          atomicAdd(&hist[(u >> (p * 8)) & 255u], 1u);
      }
      __syncthreads();
      // inclusive suffix sum over buckets (descending select)
      const unsigned int v = hist[t];
      unsigned int s = v;
#pragma unroll
      for (int off = 1; off < 64; off <<= 1) {
        const unsigned int o = __shfl_down(s, off);
        if (lane + off < 64) s += o;
      }
      if (lane == 0) wq[w] = s;
      __syncthreads();
      unsigned int hi = 0;
      for (int q = w + 1; q < 4; ++q) hi += wq[q];
      const unsigned int Ssuf = s + hi;          // sum of buckets >= t
      const unsigned int Snext = Ssuf - v;       // sum of buckets >  t
      if (Ssuf >= krem && Snext < krem) {        // unique winner
        sb[0] = pref | ((unsigned int)t << (p * 8));
        sb[1] = above + Snext;
        sb[2] = krem - Snext;
        sb[3] = 0u;
      }
      __syncthreads();
      pref = sb[0]; above = sb[1]; krem = sb[2];
    }
    // T = pref; 'above' strictly greater; take 'krem' ties lowest-index.
    const int off = b * 128 + mode * 64;
    unsigned int myties = 0;
    for (int j = 0; j < 64; ++j) {
      unsigned int u = uv[fvx(i0 + j)];
      if (mode) u = ~u;
      if (u > pref) {
        const unsigned int pos = atomicAdd(&sb[3], 1u);
        sel[off + pos] = i0 + j;
      } else if (u == pref) {
        myties++;
      }
    }
    // exclusive prefix of myties in thread order (wave shfl + cross-wave)
    unsigned int pv = myties;
#pragma unroll
    for (int offp = 1; offp < 64; offp <<= 1) {
      const unsigned int o = __shfl_up(pv, offp);
      if (lane >= offp) pv += o;
    }
    __syncthreads();           // wq free (selection passes done)
    if (lane == 63) wq[w] = pv;
    __syncthreads();
    unsigned int base = 0;
    for (int q = 0; q < w; ++q) base += wq[q];
    unsigned int g = base + pv - myties;
    for (int j = 0; j < 64 && myties > 0; ++j) {
      unsigned int u = uv[fvx(i0 + j)];
      if (mode) u = ~u;
      if (u == pref) {
        if (g < krem) sel[off + above + g] = i0 + j;
        g++;
        myties--;
      }
    }
    __syncthreads();
  }
}

// ---------------------------------------------------------------------------
// Kernel 3: z[b][d] += sum_n softmax-weight(n) * X[b][n][d]   (f32 atomics)
// ---------------------------------------------------------------------------
__global__ __launch_bounds__(256) void k_zacc(
    const float* __restrict__ X, const float* __restrict__ f,
    const float* __restrict__ mask, const float* __restrict__ ms,
    const float* __restrict__ Zs, float* __restrict__ zv) {
  const int b = blockIdx.x >> 6;
  const int chunk = blockIdx.x & 63;
  const int t = threadIdx.x;
  const int d = t * 4;
  const float m = ms[b];
  const float inv = 1.0f / Zs[b];
  const int n0 = chunk * (NN / 64);
  const float* Xb = X + ((size_t)b * NN + n0) * DD;
  const float* fb = f + (size_t)b * NN + n0;
  const float* kb = mask + (size_t)b * NN + n0;
  float4 acc = make_float4(0.f, 0.f, 0.f, 0.f);
#pragma unroll 4
  for (int n = 0; n < NN / 64; ++n) {
    const float wgt = kb[n] > 0.f ? expf(fb[n] - m) * inv : 0.f;
    const float4 x = *(const float4*)(Xb + (size_t)n * DD + d);
    acc.x = fmaf(wgt, x.x, acc.x);
    acc.y = fmaf(wgt, x.y, acc.y);
    acc.z = fmaf(wgt, x.z, acc.z);
    acc.w = fmaf(wgt, x.w, acc.w);
  }
  float* zb = zv + b * DD + d;
  atomicAdd(zb + 0, acc.x);
  atomicAdd(zb + 1, acc.y);
  atomicAdd(zb + 2, acc.z);
  atomicAdd(zb + 3, acc.w);
}

// ---------------------------------------------------------------------------
// Kernel 4: bag_pred, crit_loss, instance smooth-top1-SVM losses.
// ---------------------------------------------------------------------------
__global__ __launch_bounds__(256) void k_final(
    const float* __restrict__ X, const float* __restrict__ zv,
    const float* __restrict__ Wc, const float* __restrict__ bc,
    const int* __restrict__ labels, const int* __restrict__ sel,
    const float* __restrict__ Wi, const float* __restrict__ bi,
    float* __restrict__ out) {
  const int b = blockIdx.x;
  const int t = threadIdx.x;
  const int lane = t & 63, w = t >> 6;
  __shared__ float sin_[4], sout_[4];
  const int label = labels[b];

  if (w == 0) {
    float s = 0.f;
    const float* zb = zv + b * DD;
#pragma unroll
    for (int j = 0; j < 16; j += 4) {
      const float4 a = *(const float4*)(zb + lane * 16 + j);
      const float4 c = *(const float4*)(Wc + lane * 16 + j);
      s += a.x * c.x + a.y * c.y + a.z * c.z + a.w * c.w;
    }
#pragma unroll
    for (int sh = 1; sh < 64; sh <<= 1) s += __shfl_xor(s, sh);
    if (lane == 0) {
      const float bp = s + bc[0];
      out[b] = bp;
      const float lf = (float)label;
      atomicAdd(out + 8, (softplusf(bp) - bp * lf) * 0.125f);
    }
  }

  const float* Win = Wi + label * (DD * 2);
  const float* Wot = Wi + (1 - label) * (DD * 2);
  const float bin0 = bi[label * 2], bin1 = bi[label * 2 + 1];
  const float bo0 = bi[(1 - label) * 2], bo1 = bi[(1 - label) * 2 + 1];
  float ain = 0.f, aout = 0.f;
  for (int r = w; r < 128; r += 4) {
    const int id = sel[b * 128 + r];
    const float* xr = X + ((size_t)b * NN + id) * DD;
    float p0 = 0.f, p1 = 0.f, p2 = 0.f, p3 = 0.f;
#pragma unroll
    for (int j = 0; j < 16; j += 4) {
      const int d = lane * 16 + j;
      const float4 x = *(const float4*)(xr + d);
      const float4 wa = *(const float4*)(Win + d * 2);
      const float4 wb = *(const float4*)(Win + d * 2 + 4);
      p0 += x.x * wa.x + x.y * wa.z + x.z * wb.x + x.w * wb.z;
      p1 += x.x * wa.y + x.y * wa.w + x.z * wb.y + x.w * wb.w;
      if (r < 64) {
        const float4 oa = *(const float4*)(Wot + d * 2);
        const float4 ob = *(const float4*)(Wot + d * 2 + 4);
        p2 += x.x * oa.x + x.y * oa.z + x.z * ob.x + x.w * ob.z;
        p3 += x.x * oa.y + x.y * oa.w + x.z * ob.y + x.w * ob.w;
      }
    }
#pragma unroll
    for (int sh = 1; sh < 64; sh <<= 1) {
      p0 += __shfl_xor(p0, sh);
      p1 += __shfl_xor(p1, sh);
      p2 += __shfl_xor(p2, sh);
      p3 += __shfl_xor(p3, sh);
    }
    if (lane == 0) {
      const float l0 = p0 + bin0, l1 = p1 + bin1;
      ain += (r < 64) ? softplusf(l0 + 1.f - l1) : softplusf(l1 + 1.f - l0);
      if (r < 64) aout += softplusf((p3 + bo1) + 1.f - (p2 + bo0));
    }
  }
  if (lane == 0) { sin_[w] = ain; sout_[w] = aout; }
  __syncthreads();
  if (t == 0) {
    const float ti = sin_[0] + sin_[1] + sin_[2] + sin_[3];
    const float to = sout_[0] + sout_[1] + sout_[2] + sout_[3];
    atomicAdd(out + 9, ti * (1.0f / 128.0f) + to * (1.0f / 64.0f));
  }
}

// ---------------------------------------------------------------------------

extern "C" void kernel_launch(void* const* d_in, const int* in_sizes, int n_in,
                              void* d_out, int out_size, void* d_ws, size_t ws_size,
                              hipStream_t stream) {
  const float* X      = (const float*)d_in[0];
  const float* mask   = (const float*)d_in[1];
  const int*   labels = (const int*)d_in[2];
  const float* W1     = (const float*)d_in[3];
  const float* b1     = (const float*)d_in[4];
  const float* w2     = (const float*)d_in[5];
  const float* b2     = (const float*)d_in[6];
  const float* Wc     = (const float*)d_in[7];
  const float* bc     = (const float*)d_in[8];
  const float* Wi     = (const float*)d_in[9];
  const float* bi     = (const float*)d_in[10];
  float* out = (float*)d_out;

  float* ws  = (float*)d_ws;
  float* f   = ws;                            // 131072 f32
  float* ms  = ws + 131072;                   // 8
  float* Zs  = ws + 131080;                   // 8
  float* zv  = ws + 131088;                   // 8192
  int*   sel = (int*)(ws + 139280);           // 1024 int
  unsigned short* W1T = (unsigned short*)(ws + 140304);  // 131072 bf16

  k_prep  <<<512,  256, 0, stream>>>(W1, W1T, zv, out);
  k_scores<<<1024, 256, 0, stream>>>(X, W1T, b1, w2, b2, f);
  k_select<<<8,    256, 0, stream>>>(f, mask, ms, Zs, sel);
  k_zacc  <<<512,  256, 0, stream>>>(X, f, mask, ms, Zs, zv);
  k_final <<<8,    256, 0, stream>>>(X, zv, Wc, bc, labels, sel, Wi, bi, out);
}